// Round 2
// baseline (1277.915 us; speedup 1.0000x reference)
//
#include <hip/hip_runtime.h>
#include <cmath>

constexpr int BN = 4, CN = 128, HN = 256, WN = 256;
constexpr int NPLANE = BN * CN;          // 512
constexpr int PLANE  = HN * WN;          // 65536

// workspace layout (float offsets); end = 39,146,496 floats = 157 MB
constexpr long long OF_THR = 0;                                  // 1024
constexpr long long OF_R1  = 1024;                               // 2*512*128*128
constexpr long long OF_D1  = OF_R1 + 2LL * NPLANE * 128 * 128;
constexpr long long OF_D2  = OF_D1 + 2LL * NPLANE * 128 * 128;
constexpr long long OF_D3  = OF_D2 + 2LL * NPLANE * 64 * 64;
constexpr long long OF_D4  = OF_D3 + 2LL * NPLANE * 32 * 32;
constexpr long long OF_D5  = OF_D4 + 2LL * NPLANE * 16 * 16;
constexpr long long OF_D6  = OF_D5 + 2LL * NPLANE * 8 * 8;
constexpr long long OF_D7  = OF_D6 + 2LL * NPLANE * 4 * 4;

static __device__ __forceinline__ float sigm100(float a, float thr) {
    return 1.f / (1.f + __expf(-100.f * (a - thr))) + 1e-6f;
}

// ---------------------------------------------------------------- stats ----
// per-plane mean + unbiased std of relu(x) and relu(-x) -> thresholds
__global__ __launch_bounds__(256) void stats_kernel(const float* __restrict__ x,
                                                    float* __restrict__ ws) {
    int p = blockIdx.x;            // 0..511
    int tid = threadIdx.x;
    const float* xp = x + (long long)p * PLANE;
    double sp = 0, spp = 0, sn = 0, snn = 0;
    for (int i = tid; i < PLANE; i += 256) {
        float v = xp[i];
        float a = fmaxf(v, 0.f);
        float b = fmaxf(-v, 0.f);
        sp += a; spp += (double)a * a;
        sn += b; snn += (double)b * b;
    }
    __shared__ double red[256];
    double vals[4] = {sp, spp, sn, snn};
    double out4[4];
    for (int q = 0; q < 4; q++) {
        red[tid] = vals[q];
        __syncthreads();
        for (int s = 128; s > 0; s >>= 1) {
            if (tid < s) red[tid] += red[tid + s];
            __syncthreads();
        }
        out4[q] = red[0];
        __syncthreads();
    }
    if (tid == 0) {
        double N = (double)PLANE;
        double meanP = out4[0] / N, meanN = out4[2] / N;
        double varP = (out4[1] - out4[0] * out4[0] / N) / (N - 1.0);
        double varN = (out4[3] - out4[2] * out4[2] / N) / (N - 1.0);
        varP = varP > 0 ? varP : 0;
        varN = varN > 0 ? varN : 0;
        ws[OF_THR + p]       = (float)(meanP + 2.0 * sqrt(varP));
        ws[OF_THR + 512 + p] = (float)(meanN + 2.0 * sqrt(varN));
    }
}

// -------------------------------------------------- field -> r1 only ----
// one block = one 64x64 tile of one plane, both signs. The 256->128
// align-corners resize partitions exactly along 64-px tiles (support of
// output chunk [32t,32t+31] is inside input rows [64t,64t+63]), so each
// block emits its 32x32 chunk of r1 = resize(pool3(field)*gamma, 128,128)
// without ever materializing the full-res pooled field.
__global__ __launch_bounds__(256) void field_kernel(const float* __restrict__ x,
                                                    float* __restrict__ ws) {
    const int tile = blockIdx.x;           // 0..15  (ty*4+tx)
    const int p = blockIdx.y;              // 0..511
    const int ty = tile >> 2, tx = tile & 3;
    const int y0 = ty * 64, x0 = tx * 64;
    const int tid = threadIdx.x;

    __shared__ float fP[66 * 66];
    __shared__ float fN[66 * 66];
    __shared__ float pl[64 * 64];

    const float thrP = ws[OF_THR + p];
    const float thrN = ws[OF_THR + 512 + p];
    const float* xp = x + (long long)p * PLANE;

    for (int i = tid; i < 66 * 66; i += 256) {
        int ly = i / 66, lx = i - ly * 66;
        int gy = y0 - 1 + ly, gx = x0 - 1 + lx;
        float vp = -INFINITY, vn = -INFINITY;   // -inf pad, matches MaxPool2d
        if (gy >= 0 && gy < 256 && gx >= 0 && gx < 256) {
            float v = xp[gy * 256 + gx];
            float a = fmaxf(v, 0.f), b = fmaxf(-v, 0.f);
            vp = a * sigm100(a, thrP);
            vn = b * sigm100(b, thrN);
        }
        fP[i] = vp; fN[i] = vn;
    }

    const float g1 = 0.99f;
    const float S = (float)(255.0 / 127.0);
    for (int s = 0; s < 2; s++) {
        const float* f = s ? fN : fP;
        __syncthreads();   // fields ready (s=0) / previous pl reads done (s=1)
        for (int i = tid; i < 64 * 64; i += 256) {
            int oy = i >> 6, ox = i & 63;
            const float* r0 = f + oy * 66 + ox;
            float m = fmaxf(fmaxf(r0[0], r0[1]), r0[2]);
            const float* r1r = r0 + 66;
            m = fmaxf(m, fmaxf(fmaxf(r1r[0], r1r[1]), r1r[2]));
            const float* r2 = r1r + 66;
            m = fmaxf(m, fmaxf(fmaxf(r2[0], r2[1]), r2[2]));
            pl[i] = m * g1;
        }
        __syncthreads();
        for (int i = tid; i < 32 * 32; i += 256) {
            int ry = i >> 5, rx = i & 31;
            int jy = ty * 32 + ry, jx = tx * 32 + rx;
            float uy = jy * S, ux = jx * S;
            int iy0 = (int)floorf(uy), ix0 = (int)floorf(ux);
            int iy1 = min(iy0 + 1, 255), ix1 = min(ix0 + 1, 255);
            float fy = uy - iy0, fx = ux - ix0;
            int ly0 = min(max(iy0 - y0, 0), 63), ly1 = min(max(iy1 - y0, 0), 63);
            int lx0 = min(max(ix0 - x0, 0), 63), lx1 = min(max(ix1 - x0, 0), 63);
            float a = pl[ly0 * 64 + lx0], b = pl[ly0 * 64 + lx1];
            float c = pl[ly1 * 64 + lx0], d = pl[ly1 * 64 + lx1];
            float v = (a * (1.f - fy) + c * fy) * (1.f - fx) + (b * (1.f - fy) + d * fy) * fx;
            ws[OF_R1 + (long long)(s * 512 + p) * 16384 + jy * 128 + jx] = v;
        }
    }
}

// ---------------------------------------------------------------- pool1 ----
// d1 = pool3(r1) * gamma^2
__global__ __launch_bounds__(256) void pool1_kernel(float* __restrict__ ws, float gamma2) {
    long long gid = (long long)blockIdx.x * 256 + threadIdx.x;
    int ps = (int)(gid >> 14);
    int rem = (int)(gid & 16383);
    int oy = rem >> 7, ox = rem & 127;
    const float* src = ws + OF_R1 + (long long)ps * 16384;
    float m = -INFINITY;
    for (int dy = -1; dy <= 1; dy++) {
        int yy = oy + dy;
        if (yy < 0 || yy > 127) continue;
        for (int dx = -1; dx <= 1; dx++) {
            int xx = ox + dx;
            if (xx < 0 || xx > 127) continue;
            m = fmaxf(m, src[yy * 128 + xx]);
        }
    }
    ws[OF_D1 + (long long)ps * 16384 + rem] = m * gamma2;
}

// ------------------------------------------------- pyramid step (k>=2) ----
// d_k = pool3(resize(d_{k-1}, n, n)) * gamma^(2^k), fused per output px
__global__ __launch_bounds__(256) void pstep_kernel(float* __restrict__ ws,
                                                    long long srcOff, long long dstOff,
                                                    int m, int n, int logn,
                                                    float scale, float gamma) {
    int gid = blockIdx.x * 256 + threadIdx.x;
    int ps = gid >> (2 * logn);
    int rem = gid & ((1 << (2 * logn)) - 1);
    int oy = rem >> logn, ox = rem & ((1 << logn) - 1);
    const float* src = ws + srcOff + (long long)ps * m * m;
    float best = -INFINITY;
    for (int dy = -1; dy <= 1; dy++) {
        int yy = oy + dy;
        if (yy < 0 || yy >= n) continue;
        float uy = yy * scale;
        int iy0 = (int)floorf(uy);
        if (iy0 > m - 1) iy0 = m - 1;
        int iy1 = min(iy0 + 1, m - 1);
        float fy = uy - iy0;
        for (int dx = -1; dx <= 1; dx++) {
            int xx = ox + dx;
            if (xx < 0 || xx >= n) continue;
            float ux = xx * scale;
            int ix0 = (int)floorf(ux);
            if (ix0 > m - 1) ix0 = m - 1;
            int ix1 = min(ix0 + 1, m - 1);
            float fx = ux - ix0;
            float a = src[iy0 * m + ix0], b = src[iy0 * m + ix1];
            float c = src[iy1 * m + ix0], d = src[iy1 * m + ix1];
            float v = (a * (1.f - fy) + c * fy) * (1.f - fx) + (b * (1.f - fy) + d * fy) * fx;
            best = fmaxf(best, v);
        }
    }
    ws[dstOff + (long long)ps * n * n + rem] = best * gamma;
}

// ------------------------------------------------------------- radiance ----
// one block = one 256x16 row-tile of one plane. Recomputes level-0
// cur = max(field, gamma*pool3(field)) from x in LDS (no cur buffer),
// maxes in the 7 pyramid up-resizes via per-row y-lerp + per-col x-lerp,
// writes rad = curP - curN into d_out (rad scratch; mlp overwrites it).
__global__ __launch_bounds__(256) void radiance_kernel(const float* __restrict__ x,
                                                       const float* __restrict__ ws,
                                                       float* __restrict__ rad) {
    const int tY = blockIdx.x;     // 0..15
    const int p = blockIdx.y;      // 0..511
    const int Y0 = tY * 16;
    const int tid = threadIdx.x;   // = column

    __shared__ float fP[18 * 258];   // field rows Y0-1..Y0+16, cols padded -inf
    __shared__ float fN[18 * 258];
    __shared__ float fpb[2 * 1920];  // pyramid footprints, both signs
    __shared__ float rv[2 * 256];    // per-row y-lerped level rows

    const float thrP = ws[OF_THR + p];
    const float thrN = ws[OF_THR + 512 + p];
    const float* xp = x + (long long)p * PLANE;

    // field rows into LDS (col c stored at c+1; pads at 0 and 257)
    for (int r = 0; r < 18; r++) {
        int gy = Y0 - 1 + r;
        float vp = -INFINITY, vn = -INFINITY;
        if (gy >= 0 && gy < 256) {
            float v = xp[gy * 256 + tid];
            float a = fmaxf(v, 0.f), b = fmaxf(-v, 0.f);
            vp = a * sigm100(a, thrP);
            vn = b * sigm100(b, thrN);
        }
        fP[r * 258 + tid + 1] = vp;
        fN[r * 258 + tid + 1] = vn;
    }
    if (tid < 18) {
        fP[tid * 258] = -INFINITY; fP[tid * 258 + 257] = -INFINITY;
        fN[tid * 258] = -INFINITY; fN[tid * 258 + 257] = -INFINITY;
    }

    // pyramid footprints for rows Y0..Y0+15
    int oyk[8], hyk[8], basek[8];
    int acc = 0;
#pragma unroll
    for (int k = 1; k <= 7; k++) {
        int n = 256 >> k;
        float sc = (float)(n - 1) / 255.f;
        int oy = (int)floorf(Y0 * sc);
        int ey = (int)floorf((Y0 + 15) * sc) + 1;
        if (ey > n - 1) ey = n - 1;
        oyk[k] = oy;
        hyk[k] = ey - oy + 1;
        basek[k] = acc;
        acc += hyk[k] * n;
    }
    const long long OFD[8] = {0, OF_D1, OF_D2, OF_D3, OF_D4, OF_D5, OF_D6, OF_D7};
    for (int s = 0; s < 2; s++) {
#pragma unroll
        for (int k = 1; k <= 7; k++) {
            int n = 256 >> k;
            const float* src = ws + OFD[k] + (long long)(s * 512 + p) * n * n + oyk[k] * n;
            float* dst = fpb + s * 1920 + basek[k];
            int tot = hyk[k] * n;
            for (int i = tid; i < tot; i += 256) dst[i] = src[i];
        }
    }
    __syncthreads();

    const int rvOff[8] = {0, 0, 128, 192, 224, 240, 248, 252};
    float* radp = rad + (long long)p * PLANE;

    for (int q = 0; q < 16; q++) {
        int row = Y0 + q;
        // y-lerp each level's two footprint rows into rv (fy wave-uniform)
#pragma unroll
        for (int k = 1; k <= 7; k++) {
            int n = 256 >> k;
            float sc = (float)(n - 1) / 255.f;
            float uy = row * sc;
            int iy0 = (int)floorf(uy);
            if (iy0 > n - 1) iy0 = n - 1;
            int iy1 = min(iy0 + 1, n - 1);
            float fy = uy - iy0;
            int r0 = iy0 - oyk[k], r1i = iy1 - oyk[k];
            for (int j = tid; j < n; j += 256) {
                float aP = fpb[basek[k] + r0 * n + j];
                float bP = fpb[basek[k] + r1i * n + j];
                rv[rvOff[k] + j] = aP + fy * (bP - aP);
                float aN = fpb[1920 + basek[k] + r0 * n + j];
                float bN = fpb[1920 + basek[k] + r1i * n + j];
                rv[256 + rvOff[k] + j] = aN + fy * (bN - aN);
            }
        }
        __syncthreads();
        const int col = tid;
        const int lr = q + 1;                       // LDS row of `row`
        // level 0: cur = max(field, 0.99*pool3(field))
        const float* rpP0 = fP + (lr - 1) * 258 + col;
        const float* rpP1 = rpP0 + 258;
        const float* rpP2 = rpP1 + 258;
        float pP = fmaxf(fmaxf(rpP0[0], rpP0[1]), rpP0[2]);
        pP = fmaxf(pP, fmaxf(fmaxf(rpP1[0], rpP1[1]), rpP1[2]));
        pP = fmaxf(pP, fmaxf(fmaxf(rpP2[0], rpP2[1]), rpP2[2]));
        float mP = fmaxf(rpP1[1], 0.99f * pP);
        const float* rpN0 = fN + (lr - 1) * 258 + col;
        const float* rpN1 = rpN0 + 258;
        const float* rpN2 = rpN1 + 258;
        float pN = fmaxf(fmaxf(rpN0[0], rpN0[1]), rpN0[2]);
        pN = fmaxf(pN, fmaxf(fmaxf(rpN1[0], rpN1[1]), rpN1[2]));
        pN = fmaxf(pN, fmaxf(fmaxf(rpN2[0], rpN2[1]), rpN2[2]));
        float mN = fmaxf(rpN1[1], 0.99f * pN);
        // levels 1..7: x-lerp from rv
#pragma unroll
        for (int k = 1; k <= 7; k++) {
            int n = 256 >> k;
            float sc = (float)(n - 1) / 255.f;
            float ux = col * sc;
            int jx0 = (int)floorf(ux);
            if (jx0 > n - 1) jx0 = n - 1;
            int jx1 = min(jx0 + 1, n - 1);
            float fx = ux - jx0;
            float aP = rv[rvOff[k] + jx0], bP = rv[rvOff[k] + jx1];
            mP = fmaxf(mP, aP + fx * (bP - aP));
            float aN = rv[256 + rvOff[k] + jx0], bN = rv[256 + rvOff[k] + jx1];
            mN = fmaxf(mN, aN + fx * (bN - aN));
        }
        float r = mP - mN;
        __syncthreads();           // rv reads done before next row overwrites
        radp[row * 256 + col] = r;
    }
}

// ------------------------------------------------------------------ mlp ----
// io holds rad on entry, final output on exit. Per-thread read set ==
// write set and all reads precede all writes, so in-place is safe.
__global__ __launch_bounds__(256) void mlp_kernel(const float* __restrict__ x,
                                                  const float* __restrict__ w1,
                                                  const float* __restrict__ b1,
                                                  const float* __restrict__ w2,
                                                  const float* __restrict__ b2,
                                                  float* io) {
    const int y = blockIdx.x;   // 0..255
    const int b = blockIdx.y;   // 0..3
    const int col = threadIdx.x;

    float h[16];
#pragma unroll
    for (int o = 0; o < 16; o++) h[o] = b1[o];
    for (int c = 0; c < 128; c++) {
        float r = io[(long long)(b * 128 + c) * PLANE + y * 256 + col];
#pragma unroll
        for (int o = 0; o < 16; o++) h[o] += w1[o * 128 + c] * r;
    }
#pragma unroll
    for (int o = 0; o < 16; o++) h[o] = fmaxf(h[o], 0.f);
    for (int c = 0; c < 128; c++) {
        float z = b2[c];
#pragma unroll
        for (int o = 0; o < 16; o++) z += w2[c * 16 + o] * h[o];
        float mod = 1.f / (1.f + __expf(-z));
        long long idx = (long long)(b * 128 + c) * PLANE + y * 256 + col;
        io[idx] = x[idx] * mod;
    }
}

// -------------------------------------------------------------- launcher ----
extern "C" void kernel_launch(void* const* d_in, const int* in_sizes, int n_in,
                              void* d_out, int out_size, void* d_ws, size_t ws_size,
                              hipStream_t stream) {
    (void)in_sizes; (void)n_in; (void)out_size; (void)ws_size;
    const float* x  = (const float*)d_in[0];
    const float* w1 = (const float*)d_in[1];
    const float* b1 = (const float*)d_in[2];
    const float* w2 = (const float*)d_in[3];
    const float* b2 = (const float*)d_in[4];
    float* out = (float*)d_out;
    float* ws = (float*)d_ws;

    stats_kernel<<<512, 256, 0, stream>>>(x, ws);
    field_kernel<<<dim3(16, 512), 256, 0, stream>>>(x, ws);
    pool1_kernel<<<(1024 * 16384) / 256, 256, 0, stream>>>(ws, (float)std::pow(0.99, 2.0));

    const long long dsts[8] = {0, OF_D1, OF_D2, OF_D3, OF_D4, OF_D5, OF_D6, OF_D7};
    for (int k = 2; k <= 7; k++) {
        int m = 256 >> (k - 1), n = 256 >> k;
        int logn = 8 - k;
        float scale = (float)((double)(m - 1) / (double)(n - 1));
        float gamma = (float)std::pow(0.99, (double)(1 << k));
        int total = 1024 * n * n;
        pstep_kernel<<<total / 256, 256, 0, stream>>>(ws, dsts[k - 1], dsts[k],
                                                      m, n, logn, scale, gamma);
    }
    radiance_kernel<<<dim3(16, 512), 256, 0, stream>>>(x, ws, out);
    mlp_kernel<<<dim3(256, 4), 256, 0, stream>>>(x, w1, b1, w2, b2, out);
}

// Round 3
// 882.222 us; speedup vs baseline: 1.4485x; 1.4485x over previous
//
#include <hip/hip_runtime.h>
#include <cmath>

constexpr int BN = 4, CN = 128, HN = 256, WN = 256;
constexpr int NPLANE = BN * CN;          // 512
constexpr int PLANE  = HN * WN;          // 65536

// workspace layout (float offsets); end = 39,146,496 floats = 157 MB
constexpr long long OF_THR = 0;                                  // 1024
constexpr long long OF_R1  = 1024;                               // 2*512*128*128
constexpr long long OF_D1  = OF_R1 + 2LL * NPLANE * 128 * 128;
constexpr long long OF_D2  = OF_D1 + 2LL * NPLANE * 128 * 128;
constexpr long long OF_D3  = OF_D2 + 2LL * NPLANE * 64 * 64;
constexpr long long OF_D4  = OF_D3 + 2LL * NPLANE * 32 * 32;
constexpr long long OF_D5  = OF_D4 + 2LL * NPLANE * 16 * 16;
constexpr long long OF_D6  = OF_D5 + 2LL * NPLANE * 8 * 8;
constexpr long long OF_D7  = OF_D6 + 2LL * NPLANE * 4 * 4;
// stats partials are parked in the (not yet written) D1 region.

static __device__ __forceinline__ float sigm100(float a, float thr) {
    return 1.f / (1.f + __expf(-100.f * (a - thr))) + 1e-6f;
}

// --------------------------------------------------------------- statsA ----
// partial sums per (plane, 16-row strip) -> float4 partials in D1 region
__global__ __launch_bounds__(256) void statsA_kernel(const float* __restrict__ x,
                                                     float* __restrict__ ws) {
    const int strip = blockIdx.x;   // 0..15
    const int p = blockIdx.y;       // 0..511
    const int tid = threadIdx.x;
    const float* xp = x + (long long)p * PLANE + strip * 4096;
    float sp = 0, spp = 0, sn = 0, snn = 0;
    for (int i = tid; i < 4096; i += 256) {
        float v = xp[i];
        float a = fmaxf(v, 0.f), b = fmaxf(-v, 0.f);
        sp += a; spp += a * a;
        sn += b; snn += b * b;
    }
    __shared__ float red[256];
    float vals[4] = {sp, spp, sn, snn};
    float* dst = ws + OF_D1 + ((long long)p * 16 + strip) * 4;
    for (int q = 0; q < 4; q++) {
        red[tid] = vals[q];
        __syncthreads();
        for (int s = 128; s > 0; s >>= 1) {
            if (tid < s) red[tid] += red[tid + s];
            __syncthreads();
        }
        if (tid == 0) dst[q] = red[0];
        __syncthreads();
    }
}

// --------------------------------------------------------------- statsB ----
__global__ __launch_bounds__(256) void statsB_kernel(float* __restrict__ ws) {
    int p = blockIdx.x * 256 + threadIdx.x;   // grid 2 x 256 -> 512 planes
    if (p >= 512) return;
    double sp = 0, spp = 0, sn = 0, snn = 0;
    for (int s = 0; s < 16; s++) {
        const float* src = ws + OF_D1 + ((long long)p * 16 + s) * 4;
        sp += src[0]; spp += src[1]; sn += src[2]; snn += src[3];
    }
    double N = (double)PLANE;
    double meanP = sp / N, meanN = sn / N;
    double varP = (spp - sp * sp / N) / (N - 1.0);
    double varN = (snn - sn * sn / N) / (N - 1.0);
    varP = varP > 0 ? varP : 0;
    varN = varN > 0 ? varN : 0;
    ws[OF_THR + p]       = (float)(meanP + 2.0 * sqrt(varP));
    ws[OF_THR + 512 + p] = (float)(meanN + 2.0 * sqrt(varN));
}

// -------------------------------------------------- field -> r1 only ----
// Combined-sign field c = v * sigm(|v|, thr_sign): fieldP = max(c,0),
// fieldN = max(-c,0). Clamp-duplicate halo (max/min over clamped multiset
// == over valid set, replacing the -inf pad). One block = one 64x64 tile;
// the 256->128 align-corners resize partitions exactly on 64-px tiles.
__global__ __launch_bounds__(256, 3) void field_kernel(const float* __restrict__ x,
                                                       float* __restrict__ ws) {
    const int tile = blockIdx.x;           // 0..15  (ty*4+tx)
    const int p = blockIdx.y;              // 0..511
    const int ty = tile >> 2, tx = tile & 3;
    const int y0 = ty * 64, x0 = tx * 64;
    const int tid = threadIdx.x;

    __shared__ float cf[66 * 66];
    __shared__ float plP[64 * 64];
    __shared__ float plN[64 * 64];

    const float thrP = ws[OF_THR + p];
    const float thrN = ws[OF_THR + 512 + p];
    const float* xp = x + (long long)p * PLANE;

    for (int i = tid; i < 66 * 66; i += 256) {
        int ly = i / 66, lx = i - ly * 66;
        int gy = min(max(y0 - 1 + ly, 0), 255);
        int gx = min(max(x0 - 1 + lx, 0), 255);
        float v = xp[gy * 256 + gx];
        float thr = v > 0.f ? thrP : thrN;
        cf[i] = v * sigm100(fabsf(v), thr);
    }
    __syncthreads();

    const float g1 = 0.99f;
    for (int i = tid; i < 64 * 64; i += 256) {
        int oy = i >> 6, ox = i & 63;
        const float* r0 = cf + oy * 66 + ox;
        const float* r1r = r0 + 66;
        const float* r2 = r1r + 66;
        float cmax = fmaxf(fmaxf(r0[0], r0[1]), r0[2]);
        float cmin = fminf(fminf(r0[0], r0[1]), r0[2]);
        cmax = fmaxf(cmax, fmaxf(fmaxf(r1r[0], r1r[1]), r1r[2]));
        cmin = fminf(cmin, fminf(fminf(r1r[0], r1r[1]), r1r[2]));
        cmax = fmaxf(cmax, fmaxf(fmaxf(r2[0], r2[1]), r2[2]));
        cmin = fminf(cmin, fminf(fminf(r2[0], r2[1]), r2[2]));
        plP[i] = fmaxf(cmax, 0.f) * g1;
        plN[i] = fmaxf(-cmin, 0.f) * g1;
    }
    __syncthreads();

    const float S = (float)(255.0 / 127.0);
    for (int i = tid; i < 32 * 32; i += 256) {
        int ry = i >> 5, rx = i & 31;
        int jy = ty * 32 + ry, jx = tx * 32 + rx;
        float uy = jy * S, ux = jx * S;
        int iy0 = (int)floorf(uy), ix0 = (int)floorf(ux);
        int iy1 = min(iy0 + 1, 255), ix1 = min(ix0 + 1, 255);
        float fy = uy - iy0, fx = ux - ix0;
        int ly0 = min(max(iy0 - y0, 0), 63), ly1 = min(max(iy1 - y0, 0), 63);
        int lx0 = min(max(ix0 - x0, 0), 63), lx1 = min(max(ix1 - x0, 0), 63);
        float aP = plP[ly0 * 64 + lx0], bP = plP[ly0 * 64 + lx1];
        float cP = plP[ly1 * 64 + lx0], dP = plP[ly1 * 64 + lx1];
        float vP = (aP * (1.f - fy) + cP * fy) * (1.f - fx) + (bP * (1.f - fy) + dP * fy) * fx;
        float aN = plN[ly0 * 64 + lx0], bN = plN[ly0 * 64 + lx1];
        float cN = plN[ly1 * 64 + lx0], dN = plN[ly1 * 64 + lx1];
        float vN = (aN * (1.f - fy) + cN * fy) * (1.f - fx) + (bN * (1.f - fy) + dN * fy) * fx;
        ws[OF_R1 + (long long)p * 16384 + jy * 128 + jx] = vP;
        ws[OF_R1 + (long long)(512 + p) * 16384 + jy * 128 + jx] = vN;
    }
}

// ---------------------------------------------------------------- pool1 ----
__global__ __launch_bounds__(256) void pool1_kernel(float* __restrict__ ws, float gamma2) {
    long long gid = (long long)blockIdx.x * 256 + threadIdx.x;
    int ps = (int)(gid >> 14);
    int rem = (int)(gid & 16383);
    int oy = rem >> 7, ox = rem & 127;
    const float* src = ws + OF_R1 + (long long)ps * 16384;
    float m = -INFINITY;
    for (int dy = -1; dy <= 1; dy++) {
        int yy = oy + dy;
        if (yy < 0 || yy > 127) continue;
        for (int dx = -1; dx <= 1; dx++) {
            int xx = ox + dx;
            if (xx < 0 || xx > 127) continue;
            m = fmaxf(m, src[yy * 128 + xx]);
        }
    }
    ws[OF_D1 + (long long)ps * 16384 + rem] = m * gamma2;
}

// ------------------------------------------------- pyramid step (k>=2) ----
__global__ __launch_bounds__(256) void pstep_kernel(float* __restrict__ ws,
                                                    long long srcOff, long long dstOff,
                                                    int m, int n, int logn,
                                                    float scale, float gamma) {
    int gid = blockIdx.x * 256 + threadIdx.x;
    int ps = gid >> (2 * logn);
    int rem = gid & ((1 << (2 * logn)) - 1);
    int oy = rem >> logn, ox = rem & ((1 << logn) - 1);
    const float* src = ws + srcOff + (long long)ps * m * m;
    float best = -INFINITY;
    for (int dy = -1; dy <= 1; dy++) {
        int yy = oy + dy;
        if (yy < 0 || yy >= n) continue;
        float uy = yy * scale;
        int iy0 = (int)floorf(uy);
        if (iy0 > m - 1) iy0 = m - 1;
        int iy1 = min(iy0 + 1, m - 1);
        float fy = uy - iy0;
        for (int dx = -1; dx <= 1; dx++) {
            int xx = ox + dx;
            if (xx < 0 || xx >= n) continue;
            float ux = xx * scale;
            int ix0 = (int)floorf(ux);
            if (ix0 > m - 1) ix0 = m - 1;
            int ix1 = min(ix0 + 1, m - 1);
            float fx = ux - ix0;
            float a = src[iy0 * m + ix0], b = src[iy0 * m + ix1];
            float c = src[iy1 * m + ix0], d = src[iy1 * m + ix1];
            float v = (a * (1.f - fy) + c * fy) * (1.f - fx) + (b * (1.f - fy) + d * fy) * fx;
            best = fmaxf(best, v);
        }
    }
    ws[dstOff + (long long)ps * n * n + rem] = best * gamma;
}

// ------------------------------------------------------------- radiance ----
// One block = 256x16 row-tile of one plane, both signs. Combined-sign field
// in LDS (18x258), hmax/hmin streaming for level-0 pool3 (3 LDS reads/row),
// register-cached x-lerped footprint rows for levels 1..7 (re-read only on
// wave-uniform footprint-row advance). Zero barriers in the row loop.
__global__ __launch_bounds__(256, 4) void radiance_kernel(const float* __restrict__ x,
                                                          const float* __restrict__ ws,
                                                          float* __restrict__ rad) {
    const int tY = blockIdx.x;     // 0..15
    const int p = blockIdx.y;      // 0..511
    const int Y0 = tY * 16;
    const int tid = threadIdx.x;   // = column

    __shared__ float cf[18 * 258];   // combined field rows Y0-1..Y0+16 (clamped)
    __shared__ float fpb[2 * 1920];  // pyramid footprints, both signs

    const float thrP = ws[OF_THR + p];
    const float thrN = ws[OF_THR + 512 + p];
    const float* xp = x + (long long)p * PLANE;

    // stage combined field; cols duplicated at 0 and 257 (clamp trick)
    for (int r = 0; r < 18; r++) {
        int gy = min(max(Y0 - 1 + r, 0), 255);
        float v = xp[gy * 256 + tid];
        float thr = v > 0.f ? thrP : thrN;
        float c = v * sigm100(fabsf(v), thr);
        cf[r * 258 + tid + 1] = c;
        if (tid == 0) cf[r * 258] = c;
        if (tid == 255) cf[r * 258 + 257] = c;
    }

    // footprint extents
    int oyk[8], hyk[8], basek[8];
    int acc = 0;
#pragma unroll
    for (int k = 1; k <= 7; k++) {
        int n = 256 >> k;
        float sc = (float)(n - 1) / 255.f;
        int oy = (int)floorf(Y0 * sc);
        int ey = (int)floorf((Y0 + 15) * sc) + 1;
        if (ey > n - 1) ey = n - 1;
        oyk[k] = oy; hyk[k] = ey - oy + 1; basek[k] = acc;
        acc += hyk[k] * n;
    }
    const long long OFD[8] = {0, OF_D1, OF_D2, OF_D3, OF_D4, OF_D5, OF_D6, OF_D7};
    for (int s = 0; s < 2; s++) {
#pragma unroll
        for (int k = 1; k <= 7; k++) {
            int n = 256 >> k;
            const float* src = ws + OFD[k] + (long long)(s * 512 + p) * n * n + oyk[k] * n;
            float* dst = fpb + s * 1920 + basek[k];
            int tot = hyk[k] * n;
            for (int i = tid; i < tot; i += 256) dst[i] = src[i];
        }
    }
    __syncthreads();

    // per-thread per-level x-lerp constants
    int j0[8], j1[8]; float fxk[8];
#pragma unroll
    for (int k = 1; k <= 7; k++) {
        int n = 256 >> k;
        float sc = (float)(n - 1) / 255.f;
        float ux = tid * sc;
        int a = (int)ux; if (a > n - 1) a = n - 1;
        j0[k] = a; j1[k] = min(a + 1, n - 1);
        fxk[k] = ux - (float)a;
    }

    // register cache: x-lerped footprint rows iy0 (xl0) and iy1 (xl1)
    float xl0P[8], xl1P[8], xl0N[8], xl1N[8];
    int cy[8];
#pragma unroll
    for (int k = 1; k <= 7; k++) {
        int n = 256 >> k;
        int i0 = oyk[k];
        int i1 = min(i0 + 1, n - 1);
        cy[k] = i0;
        int r1o = (i1 - oyk[k]) * n;
        float aP = fpb[basek[k] + j0[k]],        bP = fpb[basek[k] + j1[k]];
        float cP = fpb[basek[k] + r1o + j0[k]],  dP = fpb[basek[k] + r1o + j1[k]];
        xl0P[k] = aP + fxk[k] * (bP - aP);
        xl1P[k] = cP + fxk[k] * (dP - cP);
        float aN = fpb[1920 + basek[k] + j0[k]],       bN = fpb[1920 + basek[k] + j1[k]];
        float cN = fpb[1920 + basek[k] + r1o + j0[k]], dN = fpb[1920 + basek[k] + r1o + j1[k]];
        xl0N[k] = aN + fxk[k] * (bN - aN);
        xl1N[k] = cN + fxk[k] * (dN - cN);
    }

    // level-0 streaming rings (rows lr-1, lr, lr+1)
    float hx0, hx1, hx2, hn0, hn1, hn2, cc1, cc2;
    {
        int b0 = 0 * 258 + tid;
        float a = cf[b0], b = cf[b0 + 1], c = cf[b0 + 2];
        hx0 = fmaxf(fmaxf(a, b), c); hn0 = fminf(fminf(a, b), c);
        int b1 = 1 * 258 + tid;
        float d = cf[b1], e = cf[b1 + 1], f = cf[b1 + 2];
        hx1 = fmaxf(fmaxf(d, e), f); hn1 = fminf(fminf(d, e), f);
        cc1 = e;
    }

    float* radp = rad + (long long)p * PLANE + (long long)Y0 * 256 + tid;

    for (int q = 0; q < 16; q++) {
        // next field row (lr+1 = q+2)
        int bn = (q + 2) * 258 + tid;
        float a = cf[bn], b = cf[bn + 1], c = cf[bn + 2];
        hx2 = fmaxf(fmaxf(a, b), c); hn2 = fminf(fminf(a, b), c);
        cc2 = b;

        float poolmax = fmaxf(fmaxf(hx0, hx1), hx2);
        float poolmin = fminf(fminf(hn0, hn1), hn2);
        float mP = fmaxf(fmaxf(cc1, 0.f), 0.99f * fmaxf(poolmax, 0.f));
        float mN = fmaxf(fmaxf(-cc1, 0.f), 0.99f * fmaxf(-poolmin, 0.f));

        int row = Y0 + q;
#pragma unroll
        for (int k = 1; k <= 7; k++) {
            int n = 256 >> k;
            float sc = (float)(n - 1) / 255.f;
            float uy = row * sc;
            int i0 = (int)uy;
            if (i0 != cy[k]) {           // wave-uniform advance (by exactly 1)
                cy[k] = i0;
                xl0P[k] = xl1P[k]; xl0N[k] = xl1N[k];
                int i1 = min(i0 + 1, n - 1);
                int ro = (i1 - oyk[k]) * n;
                float aP = fpb[basek[k] + ro + j0[k]], bP = fpb[basek[k] + ro + j1[k]];
                xl1P[k] = aP + fxk[k] * (bP - aP);
                float aN = fpb[1920 + basek[k] + ro + j0[k]], bN = fpb[1920 + basek[k] + ro + j1[k]];
                xl1N[k] = aN + fxk[k] * (bN - aN);
            }
            float fy = uy - (float)i0;
            mP = fmaxf(mP, xl0P[k] + fy * (xl1P[k] - xl0P[k]));
            mN = fmaxf(mN, xl0N[k] + fy * (xl1N[k] - xl0N[k]));
        }
        radp[q * 256] = mP - mN;

        hx0 = hx1; hx1 = hx2;
        hn0 = hn1; hn1 = hn2;
        cc1 = cc2;
    }
}

// ------------------------------------------------------------------ mlp ----
// io holds rad on entry, final output on exit (per-thread read set == write
// set; all reads precede all writes within a thread).
__global__ __launch_bounds__(256) void mlp_kernel(const float* __restrict__ x,
                                                  const float* __restrict__ w1,
                                                  const float* __restrict__ b1,
                                                  const float* __restrict__ w2,
                                                  const float* __restrict__ b2,
                                                  float* io) {
    const int y = blockIdx.x;   // 0..255
    const int b = blockIdx.y;   // 0..3
    const int col = threadIdx.x;

    float h[16];
#pragma unroll
    for (int o = 0; o < 16; o++) h[o] = b1[o];
    for (int c = 0; c < 128; c++) {
        float r = io[(long long)(b * 128 + c) * PLANE + y * 256 + col];
#pragma unroll
        for (int o = 0; o < 16; o++) h[o] += w1[o * 128 + c] * r;
    }
#pragma unroll
    for (int o = 0; o < 16; o++) h[o] = fmaxf(h[o], 0.f);
    for (int c = 0; c < 128; c++) {
        float z = b2[c];
#pragma unroll
        for (int o = 0; o < 16; o++) z += w2[c * 16 + o] * h[o];
        float mod = 1.f / (1.f + __expf(-z));
        long long idx = (long long)(b * 128 + c) * PLANE + y * 256 + col;
        io[idx] = x[idx] * mod;
    }
}

// -------------------------------------------------------------- launcher ----
extern "C" void kernel_launch(void* const* d_in, const int* in_sizes, int n_in,
                              void* d_out, int out_size, void* d_ws, size_t ws_size,
                              hipStream_t stream) {
    (void)in_sizes; (void)n_in; (void)out_size; (void)ws_size;
    const float* x  = (const float*)d_in[0];
    const float* w1 = (const float*)d_in[1];
    const float* b1 = (const float*)d_in[2];
    const float* w2 = (const float*)d_in[3];
    const float* b2 = (const float*)d_in[4];
    float* out = (float*)d_out;
    float* ws = (float*)d_ws;

    statsA_kernel<<<dim3(16, 512), 256, 0, stream>>>(x, ws);
    statsB_kernel<<<2, 256, 0, stream>>>(ws);
    field_kernel<<<dim3(16, 512), 256, 0, stream>>>(x, ws);
    pool1_kernel<<<(1024 * 16384) / 256, 256, 0, stream>>>(ws, (float)std::pow(0.99, 2.0));

    const long long dsts[8] = {0, OF_D1, OF_D2, OF_D3, OF_D4, OF_D5, OF_D6, OF_D7};
    for (int k = 2; k <= 7; k++) {
        int m = 256 >> (k - 1), n = 256 >> k;
        int logn = 8 - k;
        float scale = (float)((double)(m - 1) / (double)(n - 1));
        float gamma = (float)std::pow(0.99, (double)(1 << k));
        int total = 1024 * n * n;
        pstep_kernel<<<total / 256, 256, 0, stream>>>(ws, dsts[k - 1], dsts[k],
                                                      m, n, logn, scale, gamma);
    }
    radiance_kernel<<<dim3(16, 512), 256, 0, stream>>>(x, ws, out);
    mlp_kernel<<<dim3(256, 4), 256, 0, stream>>>(x, w1, b1, w2, b2, out);
}